// Round 14
// baseline (598.409 us; speedup 1.0000x reference)
//
#include <hip/hip_runtime.h>

#define DEVINL __device__ __forceinline__

typedef __bf16 bf16x8 __attribute__((ext_vector_type(8)));
typedef float  f32x4  __attribute__((ext_vector_type(4)));

DEVINL unsigned short f2bf(float f) {
  return __builtin_bit_cast(unsigned short, static_cast<__bf16>(f));
}
DEVINL float bf2f(unsigned short b) {
  union { unsigned int u; float f; } v; v.u = ((unsigned int)b) << 16;
  return v.f;
}

#define GLD_LDS16(SRC, DST) \
  __builtin_amdgcn_global_load_lds((const __attribute__((address_space(1))) void*)(SRC), \
                                   (__attribute__((address_space(3))) void*)(DST), 16, 0, 0)

// ---------------------------------------------------------------------------
// Plain bf16 GEMM: C[M,N] = A[M,K] * B[N,K]^T
// EPI: 3=f32 store + res, 4=bf16 relu(x+bias), 5=f32 x+bias+res.
// SWZ: XCD A-panel grouping.
// ---------------------------------------------------------------------------
template<int EPI, bool SWZ>
__global__ __launch_bounds__(256) void gemm_bt(
    const unsigned short* __restrict__ Ap, const unsigned short* __restrict__ Bp, void* __restrict__ Cp,
    const float* __restrict__ bias, const float* __restrict__ res,
    int M, int N, int K, int lda, int ldb, int ldc)
{
  __shared__ __align__(16) char smem[16384];
  unsigned short* sB = (unsigned short*)(smem + 8192);

  const int tid = threadIdx.x;
  const int w = tid >> 6, l = tid & 63;
  const int wr = w >> 1, wc = w & 1;
  const int ntn = N >> 7;
  int tm, tn;
  if constexpr (SWZ) {
    const int x = (int)blockIdx.x & 7;
    const int g = (int)blockIdx.x >> 3;
    const int per = (M >> 7) >> 3;
    tm = x * per + g / ntn;
    tn = g - (g / ntn) * ntn;
  } else {
    tm = (int)blockIdx.x / ntn;
    tn = (int)blockIdx.x - tm * ntn;
  }

  f32x4 zero = {0.f, 0.f, 0.f, 0.f};
  f32x4 acc[4][4];
  #pragma unroll
  for (int m = 0; m < 4; ++m)
    #pragma unroll
    for (int n = 0; n < 4; ++n) acc[m][n] = zero;

  for (int k0 = 0; k0 < K; k0 += 32) {
    __syncthreads();
    const int rl = l >> 2, cl = (l & 3) << 3;
    #pragma unroll
    for (int i = 0; i < 2; ++i) {
      const unsigned short* srcA = Ap + (long)(tm*128 + w*32 + i*16 + rl) * lda + (k0 + cl);
      GLD_LDS16(srcA, (unsigned short*)smem + (w*32 + i*16) * 32);
      const unsigned short* srcB = Bp + (long)(tn*128 + w*32 + i*16 + rl) * ldb + (k0 + cl);
      GLD_LDS16(srcB, sB + (w*32 + i*16) * 32);
    }
    __syncthreads();

    bf16x8 af[4], bfr[4];
    const unsigned short* sA = (const unsigned short*)smem;
    #pragma unroll
    for (int m = 0; m < 4; ++m) {
      int row = wr*64 + m*16 + (l & 15);
      af[m] = *(const bf16x8*)(sA + row*32 + ((l >> 4) << 3));
    }
    #pragma unroll
    for (int n = 0; n < 4; ++n) {
      int row = wc*64 + n*16 + (l & 15);
      bfr[n] = *(const bf16x8*)(sB + row*32 + ((l >> 4) << 3));
    }
    #pragma unroll
    for (int m = 0; m < 4; ++m)
      #pragma unroll
      for (int n = 0; n < 4; ++n)
        acc[m][n] = __builtin_amdgcn_mfma_f32_16x16x32_bf16(af[m], bfr[n], acc[m][n], 0, 0, 0);
  }

  #pragma unroll
  for (int m = 0; m < 4; ++m) {
    #pragma unroll
    for (int n = 0; n < 4; ++n) {
      #pragma unroll
      for (int r = 0; r < 4; ++r) {
        int row = tm*128 + wr*64 + m*16 + ((l >> 4) << 2) + r;
        int col = tn*128 + wc*64 + n*16 + (l & 15);
        float v = acc[m][n][r];
        long ci = (long)row * ldc + col;
        if constexpr (EPI == 3) {
          ((float*)Cp)[ci] = v + res[ci];
        } else if constexpr (EPI == 4) {
          ((unsigned short*)Cp)[ci] = f2bf(fmaxf(v + bias[col], 0.f));
        } else if constexpr (EPI == 5) {
          ((float*)Cp)[ci] = v + bias[col] + res[ci];
        }
      }
    }
  }
}

// ---------------------------------------------------------------------------
// Fused QKV projection launch (1536 blocks):
//   [0,512)    q split-GEMM   [512,1024) k split-GEMM   [1024,1536) v GEMM^T
// ---------------------------------------------------------------------------
__global__ __launch_bounds__(256) void qkv_fused(
    const unsigned short* __restrict__ h1, const unsigned short* __restrict__ h2,
    const unsigned short* __restrict__ wq1, const unsigned short* __restrict__ wq2,
    const unsigned short* __restrict__ wk1, const unsigned short* __restrict__ wk2,
    const unsigned short* __restrict__ wv1,
    unsigned short* __restrict__ q1o, unsigned short* __restrict__ q2o,
    unsigned short* __restrict__ k1o, unsigned short* __restrict__ k2o,
    unsigned short* __restrict__ vto)
{
  __shared__ __align__(16) char smem[34816];
  const int f = (int)blockIdx.x;
  const int tid = threadIdx.x;
  const int w = tid >> 6, l = tid & 63;
  const int wr = w >> 1, wc = w & 1;

  if (f < 1024) {
    const bool isq = f < 512;
    const unsigned short* B1 = isq ? wq1 : wk1;
    const unsigned short* B2 = isq ? wq2 : wk2;
    unsigned short* C1 = isq ? q1o : k1o;
    unsigned short* C2 = isq ? q2o : k2o;
    const int sub = f & 511;
    const int x = sub & 7, g = sub >> 3;
    const int tm = x * 8 + (g >> 3);
    const int tn = g & 7;

    unsigned short* sA1 = (unsigned short*)smem;
    unsigned short* sA2 = sA1 + 4096;
    unsigned short* sB1 = sA1 + 8192;
    unsigned short* sB2 = sA1 + 12288;

    f32x4 acc[4][4];
    #pragma unroll
    for (int m = 0; m < 4; ++m)
      #pragma unroll
      for (int n = 0; n < 4; ++n) acc[m][n] = (f32x4){0.f, 0.f, 0.f, 0.f};

    const int rl = l >> 2, cl = (l & 3) << 3;

    for (int k0 = 0; k0 < 1024; k0 += 32) {
      __syncthreads();
      #pragma unroll
      for (int i = 0; i < 2; ++i) {
        const int row = w*32 + i*16;
        const long asrc = (long)(tm*128 + row + rl) * 1024 + (k0 + cl);
        const long bsrc = (long)(tn*128 + row + rl) * 1024 + (k0 + cl);
        GLD_LDS16(h1 + asrc, sA1 + row*32);
        GLD_LDS16(h2 + asrc, sA2 + row*32);
        GLD_LDS16(B1 + bsrc, sB1 + row*32);
        GLD_LDS16(B2 + bsrc, sB2 + row*32);
      }
      __syncthreads();

      bf16x8 a1[4], a2[4], bb4[4];
      int boff[4];
      #pragma unroll
      for (int m = 0; m < 4; ++m) {
        int row = wr*64 + m*16 + (l & 15);
        int aoff = row*32 + ((l >> 4) << 3);
        a1[m] = *(const bf16x8*)(sA1 + aoff);
        a2[m] = *(const bf16x8*)(sA2 + aoff);
      }
      #pragma unroll
      for (int n = 0; n < 4; ++n) {
        int row = wc*64 + n*16 + (l & 15);
        boff[n] = row*32 + ((l >> 4) << 3);
        bb4[n] = *(const bf16x8*)(sB1 + boff[n]);
      }
      #pragma unroll
      for (int m = 0; m < 4; ++m)
        #pragma unroll
        for (int n = 0; n < 4; ++n) {
          acc[m][n] = __builtin_amdgcn_mfma_f32_16x16x32_bf16(a1[m], bb4[n], acc[m][n], 0, 0, 0);
          acc[m][n] = __builtin_amdgcn_mfma_f32_16x16x32_bf16(a2[m], bb4[n], acc[m][n], 0, 0, 0);
        }
      #pragma unroll
      for (int n = 0; n < 4; ++n)
        bb4[n] = *(const bf16x8*)(sB2 + boff[n]);
      #pragma unroll
      for (int m = 0; m < 4; ++m)
        #pragma unroll
        for (int n = 0; n < 4; ++n)
          acc[m][n] = __builtin_amdgcn_mfma_f32_16x16x32_bf16(a1[m], bb4[n], acc[m][n], 0, 0, 0);
    }

    #pragma unroll
    for (int m = 0; m < 4; ++m)
      #pragma unroll
      for (int n = 0; n < 4; ++n)
        #pragma unroll
        for (int r = 0; r < 4; ++r) {
          int row = tm*128 + wr*64 + m*16 + ((l >> 4) << 2) + r;
          int col = tn*128 + wc*64 + n*16 + (l & 15);
          float v = acc[m][n][r];
          long ci = (long)row * 1024 + col;
          unsigned short hv = f2bf(v);
          C1[ci] = hv;
          C2[ci] = f2bf(v - bf2f(hv));
        }
  } else {
    const int vp = f - 1024;
    const int bbv = vp >> 6;
    const int rem = vp & 63;
    const int tm = rem >> 3, tn = rem & 7;
    const long offA = (long)bbv * 1048576;
    const long offC = (long)bbv * 1048576;
    unsigned short* sB = (unsigned short*)(smem + 8192);

    f32x4 acc[4][4];
    #pragma unroll
    for (int m = 0; m < 4; ++m)
      #pragma unroll
      for (int n = 0; n < 4; ++n) acc[m][n] = (f32x4){0.f, 0.f, 0.f, 0.f};

    for (int k0 = 0; k0 < 1024; k0 += 32) {
      __syncthreads();
      const int rl = l >> 2, cl = (l & 3) << 3;
      #pragma unroll
      for (int i = 0; i < 2; ++i) {
        const unsigned short* srcA = h1 + offA + (long)(tm*128 + w*32 + i*16 + rl) * 1024 + (k0 + cl);
        GLD_LDS16(srcA, (unsigned short*)smem + (w*32 + i*16) * 32);
        const unsigned short* srcB = wv1 + (long)(tn*128 + w*32 + i*16 + rl) * 1024 + (k0 + cl);
        GLD_LDS16(srcB, sB + (w*32 + i*16) * 32);
      }
      __syncthreads();

      bf16x8 af[4], bfr[4];
      const unsigned short* sA = (const unsigned short*)smem;
      #pragma unroll
      for (int m = 0; m < 4; ++m) {
        int row = wr*64 + m*16 + (l & 15);
        af[m] = *(const bf16x8*)(sA + row*32 + ((l >> 4) << 3));
      }
      #pragma unroll
      for (int n = 0; n < 4; ++n) {
        int row = wc*64 + n*16 + (l & 15);
        bfr[n] = *(const bf16x8*)(sB + row*32 + ((l >> 4) << 3));
      }
      #pragma unroll
      for (int m = 0; m < 4; ++m)
        #pragma unroll
        for (int n = 0; n < 4; ++n)
          acc[m][n] = __builtin_amdgcn_mfma_f32_16x16x32_bf16(af[m], bfr[n], acc[m][n], 0, 0, 0);
    }

    __syncthreads();
    unsigned short* sT = (unsigned short*)smem;
    #pragma unroll
    for (int m = 0; m < 4; ++m)
      #pragma unroll
      for (int n = 0; n < 4; ++n)
        #pragma unroll
        for (int r = 0; r < 4; ++r) {
          int rowl = wr*64 + m*16 + ((l >> 4) << 2) + r;
          int coll = wc*64 + n*16 + (l & 15);
          sT[coll*136 + rowl] = f2bf(acc[m][n][r]);
        }
    __syncthreads();
    #pragma unroll
    for (int i = 0; i < 8; ++i) {
      int idx = tid + i*256;
      int c = idx >> 4, ch = idx & 15;
      bf16x8 vv = *(const bf16x8*)(sT + c*136 + ch*8);
      *(bf16x8*)(vto + offC + (long)(tn*128 + c)*1024 + (tm*128 + ch*8)) = vv;
    }
  }
}

// ---------------------------------------------------------------------------
// Fused attention v9: 64 q-rows/block (grid 1024), 512 thr / 8 waves.
// ---------------------------------------------------------------------------
__global__ __launch_bounds__(512, 2) void attn_fused(
    const unsigned short* __restrict__ q1, const unsigned short* __restrict__ q2,
    const unsigned short* __restrict__ kn1, const unsigned short* __restrict__ kn2,
    const unsigned short* __restrict__ vt, const unsigned int* __restrict__ mbits,
    float* __restrict__ attn, unsigned short* __restrict__ outm)
{
  __shared__ __align__(16) char smem[131072];  // q(32K)/red(2K) then P(128K)
  char* q1l = smem;
  char* q2l = smem + 16384;
  float* red = (float*)(smem + 32768);

  const int tid = threadIdx.x;
  const int w = tid >> 6, l = tid & 63;
  const int l15 = l & 15, l4 = l >> 4;

  const int f = (int)blockIdx.x;
  const int xcd = f & 7;
  const int j = f >> 3;
  const int z = xcd * 8 + (j >> 4);
  const int row0 = (j & 15) * 64;

  const int bb = z >> 3, hh = z & 7;
  const long base = (long)bb * 1048576;
  const int ocol = hh * 128;
  const int key0 = w * 128;

  #pragma unroll
  for (int rep = 0; rep < 2; ++rep) {
    int idx = rep*512 + tid;
    int row = idx >> 4;
    int g   = idx & 15;
    long gsrc = base + (long)(row0 + row) * 1024 + (ocol + g*8);
    int byte = (row*256 + g*16) ^ ((row & 7) << 4);
    *(bf16x8*)(q1l + byte) = *(const bf16x8*)(q1 + gsrc);
    *(bf16x8*)(q2l + byte) = *(const bf16x8*)(q2 + gsrc);
  }
  __syncthreads();

  f32x4 s[4][8];
  #pragma unroll
  for (int mf = 0; mf < 4; ++mf)
    #pragma unroll
    for (int nf = 0; nf < 8; ++nf) s[mf][nf] = (f32x4){0.f, 0.f, 0.f, 0.f};

  #pragma unroll
  for (int ks = 0; ks < 4; ++ks) {
    bf16x8 a1[4], a2[4];
    #pragma unroll
    for (int mf = 0; mf < 4; ++mf) {
      int row = mf*16 + l15;
      int byte = (row*256 + (ks*32 + l4*8)*2) ^ ((row & 7) << 4);
      a1[mf] = *(const bf16x8*)(q1l + byte);
      a2[mf] = *(const bf16x8*)(q2l + byte);
    }
    #pragma unroll
    for (int np = 0; np < 4; ++np) {
      bf16x8 b1[2], b2[2];
      #pragma unroll
      for (int t = 0; t < 2; ++t) {
        int nf = np*2 + t;
        long bi = base + (long)(key0 + nf*16 + l15) * 1024 + (ocol + ks*32 + l4*8);
        b1[t] = *(const bf16x8*)(kn1 + bi);
        b2[t] = *(const bf16x8*)(kn2 + bi);
      }
      #pragma unroll
      for (int t = 0; t < 2; ++t) {
        int nf = np*2 + t;
        #pragma unroll
        for (int mf = 0; mf < 4; ++mf) {
          s[mf][nf] = __builtin_amdgcn_mfma_f32_16x16x32_bf16(a1[mf], b1[t], s[mf][nf], 0, 0, 0);
          s[mf][nf] = __builtin_amdgcn_mfma_f32_16x16x32_bf16(a2[mf], b1[t], s[mf][nf], 0, 0, 0);
          s[mf][nf] = __builtin_amdgcn_mfma_f32_16x16x32_bf16(a1[mf], b2[t], s[mf][nf], 0, 0, 0);
        }
      }
    }
  }

  #pragma unroll
  for (int mf = 0; mf < 4; ++mf) {
    #pragma unroll
    for (int r = 0; r < 4; ++r) {
      int mg = row0 + mf*16 + l4*4 + r;
      const unsigned int* wrow = mbits + (long)bb*32768 + (long)mg*32 + w*4;
      unsigned int wd[4];
      #pragma unroll
      for (int jj = 0; jj < 4; ++jj) wd[jj] = wrow[jj];
      #pragma unroll
      for (int nf = 0; nf < 8; ++nf) {
        unsigned int bit = (wd[nf >> 1] >> (((nf & 1) << 4) + l15)) & 1u;
        if (!bit) s[mf][nf][r] = -1e9f;
      }
    }
  }

  float mx[4][4];
  #pragma unroll
  for (int mf = 0; mf < 4; ++mf)
    #pragma unroll
    for (int r = 0; r < 4; ++r) {
      float m = s[mf][0][r];
      #pragma unroll
      for (int nf = 1; nf < 8; ++nf) m = fmaxf(m, s[mf][nf][r]);
      #pragma unroll
      for (int o = 1; o < 16; o <<= 1) m = fmaxf(m, __shfl_xor(m, o, 64));
      if (l15 == 0) red[w*64 + mf*16 + l4*4 + r] = m;
    }
  __syncthreads();
  #pragma unroll
  for (int mf = 0; mf < 4; ++mf)
    #pragma unroll
    for (int r = 0; r < 4; ++r) {
      int ml = mf*16 + l4*4 + r;
      float m = red[ml];
      #pragma unroll
      for (int ww = 1; ww < 8; ++ww) m = fmaxf(m, red[ww*64 + ml]);
      mx[mf][r] = m;
    }
  __syncthreads();

  float sm[4][4];
  #pragma unroll
  for (int mf = 0; mf < 4; ++mf)
    #pragma unroll
    for (int r = 0; r < 4; ++r) sm[mf][r] = 0.f;
  #pragma unroll
  for (int mf = 0; mf < 4; ++mf)
    #pragma unroll
    for (int nf = 0; nf < 8; ++nf)
      #pragma unroll
      for (int r = 0; r < 4; ++r) {
        float e = __expf(s[mf][nf][r] - mx[mf][r]);
        s[mf][nf][r] = e;
        sm[mf][r] += e;
      }
  #pragma unroll
  for (int mf = 0; mf < 4; ++mf)
    #pragma unroll
    for (int r = 0; r < 4; ++r) {
      float t = sm[mf][r];
      #pragma unroll
      for (int o = 1; o < 16; o <<= 1) t += __shfl_xor(t, o, 64);
      if (l15 == 0) red[w*64 + mf*16 + l4*4 + r] = t;
    }
  __syncthreads();
  float inv[4][4];
  #pragma unroll
  for (int mf = 0; mf < 4; ++mf)
    #pragma unroll
    for (int r = 0; r < 4; ++r) {
      int ml = mf*16 + l4*4 + r;
      float t = red[ml];
      #pragma unroll
      for (int ww = 1; ww < 8; ++ww) t += red[ww*64 + ml];
      inv[mf][r] = 1.f / t;
    }
  __syncthreads();

  float* arow = attn + (long)(bb*8 + hh) * 1048576;
  #pragma unroll
  for (int mf = 0; mf < 4; ++mf)
    #pragma unroll
    for (int nf = 0; nf < 8; ++nf)
      #pragma unroll
      for (int r = 0; r < 4; ++r) {
        int ml = mf*16 + l4*4 + r;
        int kcol = key0 + nf*16 + l15;
        float a = s[mf][nf][r] * inv[mf][r];
        int byte = (ml*2048 + kcol*2) ^ ((ml & 7) << 4);
        *(unsigned short*)(smem + byte) = f2bf(a);
        arow[(long)(row0 + ml) * 1024 + kcol] = a;
      }
  asm volatile("s_waitcnt lgkmcnt(0)" ::: "memory");
  __builtin_amdgcn_sched_barrier(0);
  __builtin_amdgcn_s_barrier();
  __builtin_amdgcn_sched_barrier(0);

  f32x4 o[4];
  #pragma unroll
  for (int mf = 0; mf < 4; ++mf) o[mf] = (f32x4){0.f, 0.f, 0.f, 0.f};
  #pragma unroll
  for (int kq = 0; kq < 8; ++kq) {
    bf16x8 vb[4];
    #pragma unroll
    for (int t = 0; t < 4; ++t) {
      int kb = (kq*4 + t)*32 + l4*8;
      vb[t] = *(const bf16x8*)(vt + base + (long)(ocol + w*16 + l15) * 1024 + kb);
    }
    #pragma unroll
    for (int t = 0; t < 4; ++t) {
      int kb = (kq*4 + t)*32 + l4*8;
      bf16x8 pa[4];
      #pragma unroll
      for (int mf = 0; mf < 4; ++mf) {
        int ml = mf*16 + l15;
        int byte = (ml*2048 + kb*2) ^ ((ml & 7) << 4);
        pa[mf] = *(const bf16x8*)(smem + byte);
      }
      #pragma unroll
      for (int mf = 0; mf < 4; ++mf)
        o[mf] = __builtin_amdgcn_mfma_f32_16x16x32_bf16(pa[mf], vb[t], o[mf], 0, 0, 0);
    }
  }

  #pragma unroll
  for (int mf = 0; mf < 4; ++mf)
    #pragma unroll
    for (int r = 0; r < 4; ++r) {
      int row = row0 + mf*16 + l4*4 + r;
      int col = ocol + w*16 + l15;
      outm[(long)(bb*1024 + row) * 1024 + col] = f2bf(o[mf][r]);
    }
}

// ---------------------------------------------------------------------------
// prep: all weight casts/splits + mask bit-pack in ONE launch (8192 blocks).
// ---------------------------------------------------------------------------
__global__ __launch_bounds__(256) void prep(
    const float* __restrict__ wq, const float* __restrict__ wk,
    const float* __restrict__ wv, const float* __restrict__ wo,
    const float* __restrict__ w1, const float* __restrict__ w2,
    const int* __restrict__ mask,
    unsigned short* __restrict__ wq1, unsigned short* __restrict__ wq2,
    unsigned short* __restrict__ wk1, unsigned short* __restrict__ wk2,
    unsigned short* __restrict__ wv1, unsigned short* __restrict__ wob,
    unsigned short* __restrict__ w1b, unsigned short* __restrict__ w2b,
    unsigned int* __restrict__ bits)
{
  const int f = (int)blockIdx.x;
  const int tid = threadIdx.x;
  if (f < 2048) {
    const float* src = (f < 1024) ? wq : wk;
    unsigned short* hi = (f < 1024) ? wq1 : wk1;
    unsigned short* lo = (f < 1024) ? wq2 : wk2;
    long i = (long)(f & 1023) * 256 + tid;
    float4 v = ((const float4*)src)[i];
    ushort4 h, l4;
    h.x = f2bf(v.x); l4.x = f2bf(v.x - bf2f(h.x));
    h.y = f2bf(v.y); l4.y = f2bf(v.y - bf2f(h.y));
    h.z = f2bf(v.z); l4.z = f2bf(v.z - bf2f(h.z));
    h.w = f2bf(v.w); l4.w = f2bf(v.w - bf2f(h.w));
    ((ushort4*)hi)[i] = h;
    ((ushort4*)lo)[i] = l4;
  } else if (f < 6144) {
    const int sel = (f - 2048) >> 10;
    const float* src = (sel == 0) ? wv : (sel == 1) ? wo : (sel == 2) ? w1 : w2;
    unsigned short* dst = (sel == 0) ? wv1 : (sel == 1) ? wob : (sel == 2) ? w1b : w2b;
    long i = (long)((f - 2048) & 1023) * 256 + tid;
    float4 v = ((const float4*)src)[i];
    ushort4 h;
    h.x = f2bf(v.x); h.y = f2bf(v.y); h.z = f2bf(v.z); h.w = f2bf(v.w);
    ((ushort4*)dst)[i] = h;
  } else {
    int w = tid >> 6, l = tid & 63;
    long rowid = (long)(f - 6144) * 4 + w;
    const int* mrow = mask + rowid * 1024;
    unsigned int* brow = bits + rowid * 32;
    #pragma unroll
    for (int it = 0; it < 16; ++it) {
      unsigned long long b = __ballot(mrow[it*64 + l] != 0);
      if (l == 0) { brow[it*2] = (unsigned int)b; brow[it*2 + 1] = (unsigned int)(b >> 32); }
    }
  }
}

// ---------------------------------------------------------------------------
// LayerNorm stats pass 1 (per-batch partials over (d_model, seq)).
// ---------------------------------------------------------------------------
__global__ __launch_bounds__(256) void ln_stats1(const float* __restrict__ x, float2* __restrict__ part) {
  __shared__ float2 sred[4];
  int b = blockIdx.y, blk = blockIdx.x;
  const float4* xp = (const float4*)(x + (long)b * 1048576 + (long)blk * 8192);
  float s = 0.f, ss = 0.f;
  for (int i = threadIdx.x; i < 2048; i += 256) {
    float4 v = xp[i];
    s  += v.x + v.y + v.z + v.w;
    ss += v.x*v.x + v.y*v.y + v.z*v.z + v.w*v.w;
  }
  #pragma unroll
  for (int o = 32; o; o >>= 1) { s += __shfl_down(s, o, 64); ss += __shfl_down(ss, o, 64); }
  if ((threadIdx.x & 63) == 0) sred[threadIdx.x >> 6] = make_float2(s, ss);
  __syncthreads();
  if (threadIdx.x == 0) {
    float S = 0.f, SS = 0.f;
    #pragma unroll
    for (int j = 0; j < 4; ++j) { S += sred[j].x; SS += sred[j].y; }
    part[b * 128 + blk] = make_float2(S, SS);
  }
}

// ---------------------------------------------------------------------------
// ln_apply with inline final stats reduce (folds old ln_stats2):
// every block re-reduces its batch's 128 partials (fixed serial order ->
// deterministic, identical across blocks).
// ---------------------------------------------------------------------------
template<bool LO>
__global__ __launch_bounds__(256) void ln_apply(const float* __restrict__ x, const float* __restrict__ g,
                                                const float* __restrict__ be, const float2* __restrict__ part,
                                                float invN, float eps,
                                                unsigned short* __restrict__ hi, unsigned short* __restrict__ lo) {
  long i = (long)blockIdx.x * 256 + threadIdx.x;
  long e = i << 2;
  int b   = (int)(e >> 20);
  int rem = (int)(e & 1048575);
  const float2* pb = part + b * 128;
  float S = 0.f, SS = 0.f;
  #pragma unroll 8
  for (int j = 0; j < 128; ++j) { float2 p = pb[j]; S += p.x; SS += p.y; }
  float mu = S * invN;
  float rs = rsqrtf(SS * invN - mu * mu + eps);

  float4 xv = ((const float4*)x)[i];
  float4 gv = *(const float4*)(g + rem);
  float4 bv = *(const float4*)(be + rem);
  float h0 = (xv.x - mu) * rs * gv.x + bv.x;
  float h1 = (xv.y - mu) * rs * gv.y + bv.y;
  float h2 = (xv.z - mu) * rs * gv.z + bv.z;
  float h3 = (xv.w - mu) * rs * gv.w + bv.w;
  ushort4 h;
  h.x = f2bf(h0); h.y = f2bf(h1); h.z = f2bf(h2); h.w = f2bf(h3);
  ((ushort4*)hi)[i] = h;
  if (LO) {
    ushort4 l4;
    l4.x = f2bf(h0 - bf2f(h.x)); l4.y = f2bf(h1 - bf2f(h.y));
    l4.z = f2bf(h2 - bf2f(h.z)); l4.w = f2bf(h3 - bf2f(h.w));
    ((ushort4*)lo)[i] = l4;
  }
}

// k-head-norm from split bf16 k, vectorized: 4 d-columns per thread.
__global__ __launch_bounds__(256) void knorm_split2(const unsigned short* __restrict__ k1,
                                                    const unsigned short* __restrict__ k2,
                                                    unsigned short* __restrict__ kn1,
                                                    unsigned short* __restrict__ kn2) {
  int t = blockIdx.x * 256 + threadIdx.x;   // 256K threads: (b, m, d4)
  int b = t >> 15;
  int rem = t & 32767;
  int m = rem >> 5;
  int d4 = rem & 31;
  long base = (long)b * 1048576 + (long)m * 1024 + d4 * 4;
  float v[8][4];
  float s[4] = {0.f, 0.f, 0.f, 0.f};
  #pragma unroll
  for (int h = 0; h < 8; ++h) {
    ushort4 a = *(const ushort4*)(k1 + base + h * 128);
    ushort4 c = *(const ushort4*)(k2 + base + h * 128);
    v[h][0] = bf2f(a.x) + bf2f(c.x);
    v[h][1] = bf2f(a.y) + bf2f(c.y);
    v[h][2] = bf2f(a.z) + bf2f(c.z);
    v[h][3] = bf2f(a.w) + bf2f(c.w);
    #pragma unroll
    for (int d = 0; d < 4; ++d) s[d] += v[h][d] * v[h][d];
  }
  float rn[4];
  #pragma unroll
  for (int d = 0; d < 4; ++d) rn[d] = 1.f / fmaxf(sqrtf(s[d]), 1e-12f);
  #pragma unroll
  for (int h = 0; h < 8; ++h) {
    ushort4 hv, lv;
    float f0 = v[h][0] * rn[0], f1 = v[h][1] * rn[1];
    float f2 = v[h][2] * rn[2], f3 = v[h][3] * rn[3];
    hv.x = f2bf(f0); lv.x = f2bf(f0 - bf2f(hv.x));
    hv.y = f2bf(f1); lv.y = f2bf(f1 - bf2f(hv.y));
    hv.z = f2bf(f2); lv.z = f2bf(f2 - bf2f(hv.z));
    hv.w = f2bf(f3); lv.w = f2bf(f3 - bf2f(hv.w));
    *(ushort4*)(kn1 + base + h * 128) = hv;
    *(ushort4*)(kn2 + base + h * 128) = lv;
  }
}

// ---------------------------------------------------------------------------
extern "C" void kernel_launch(void* const* d_in, const int* in_sizes, int n_in,
                              void* d_out, int out_size, void* d_ws, size_t ws_size,
                              hipStream_t stream) {
  const float* enc  = (const float*)d_in[0];
  const int*   mask = (const int*)d_in[1];
  const float* ln1g = (const float*)d_in[2];
  const float* ln1b = (const float*)d_in[3];
  const float* wq   = (const float*)d_in[4];
  const float* wk   = (const float*)d_in[5];
  const float* wv   = (const float*)d_in[6];
  const float* wo   = (const float*)d_in[7];
  const float* ln2g = (const float*)d_in[8];
  const float* ln2b = (const float*)d_in[9];
  const float* w1   = (const float*)d_in[10];
  const float* b1   = (const float*)d_in[11];
  const float* w2   = (const float*)d_in[12];
  const float* b2   = (const float*)d_in[13];

  float* out_enc  = (float*)d_out;
  float* out_attn = out_enc + 8388608;   // [8, 8, 1024, 1024]

  const size_t MB = 1ull << 20;
  char* ws = (char*)d_ws;
  unsigned short* h1   = (unsigned short*)(ws + 0 * MB);     // LN1 hi  [8192,1024]
  unsigned short* h2   = (unsigned short*)(ws + 16 * MB);    // LN1 lo
  unsigned short* q1   = (unsigned short*)(ws + 32 * MB);    // q hi (later h2b)
  unsigned short* q2   = (unsigned short*)(ws + 48 * MB);    // q lo (later tb)
  unsigned short* k1r  = (unsigned short*)(ws + 64 * MB);    // k hi (raw)
  unsigned short* k2r  = (unsigned short*)(ws + 80 * MB);    // k lo (raw)
  unsigned short* kn1  = (unsigned short*)(ws + 96 * MB);    // k-normed hi
  unsigned short* kn2  = (unsigned short*)(ws + 112 * MB);   // k-normed lo
  unsigned short* vt   = (unsigned short*)(ws + 128 * MB);   // v^T per batch [b][o][m]
  unsigned short* outm = (unsigned short*)(ws + 144 * MB);   // attn@v merged [b][m][o]
  float*          x2f  = (float*)(ws + 160 * MB);            // attn-out + residual, f32
  unsigned short* h2b  = (unsigned short*)(ws + 32 * MB);    // LN2 out bf16 (reuse q1)
  unsigned short* tb   = (unsigned short*)(ws + 48 * MB);    // FFN1 out bf16 (reuse q2)
  unsigned short* wq1  = (unsigned short*)(ws + 192 * MB);
  unsigned short* wq2  = (unsigned short*)(ws + 194 * MB);
  unsigned short* wk1  = (unsigned short*)(ws + 196 * MB);
  unsigned short* wk2  = (unsigned short*)(ws + 198 * MB);
  unsigned short* wv1  = (unsigned short*)(ws + 200 * MB);
  unsigned short* wob  = (unsigned short*)(ws + 202 * MB);
  unsigned short* w1b  = (unsigned short*)(ws + 204 * MB);
  unsigned short* w2b  = (unsigned short*)(ws + 206 * MB);
  float2* part  = (float2*)(ws + 208 * MB);
  unsigned int* mbits = (unsigned int*)(ws + 209 * MB);      // 1 MB packed mask

  const float invN = 1.f / 1048576.f;

  // ---- LN1 (stats + fused apply) ----
  ln_stats1<<<dim3(128, 8), 256, 0, stream>>>(enc, part);
  ln_apply<true><<<dim3(8192), 256, 0, stream>>>(enc, ln1g, ln1b, part, invN, 1e-6f, h1, h2);

  // ---- all weight casts + mask pack in one launch ----
  prep<<<dim3(8192), 256, 0, stream>>>(wq, wk, wv, wo, w1, w2, mask,
      wq1, wq2, wk1, wk2, wv1, wob, w1b, w2b, mbits);

  // ---- q/k/v projections fused in one launch ----
  qkv_fused<<<dim3(1536), 256, 0, stream>>>(h1, h2, wq1, wq2, wk1, wk2, wv1,
      q1, q2, k1r, k2r, vt);

  // ---- k head-norm + split (vectorized) ----
  knorm_split2<<<dim3(1024), 256, 0, stream>>>(k1r, k2r, kn1, kn2);

  // ---- fused attention: logits + mask + softmax + attn store + PV ----
  attn_fused<<<dim3(1024), 512, 0, stream>>>(q1, q2, kn1, kn2, vt, mbits, out_attn, outm);

  // ---- output projection + residual (XCD-grouped) ----
  gemm_bt<3, true><<<dim3(512), 256, 0, stream>>>(outm, wob, x2f, nullptr, enc,
      8192, 1024, 1024, 1024, 1024, 1024);

  // ---- LN2 (stats + fused apply) ----
  ln_stats1<<<dim3(128, 8), 256, 0, stream>>>(x2f, part);
  ln_apply<false><<<dim3(8192), 256, 0, stream>>>(x2f, ln2g, ln2b, part, invN, 1e-6f, h2b, nullptr);

  // ---- FFN (XCD-grouped) ----
  gemm_bt<4, true><<<dim3(512), 256, 0, stream>>>(h2b, w1b, tb, b1, nullptr,
      8192, 1024, 1024, 1024, 1024, 1024);
  gemm_bt<5, true><<<dim3(512), 256, 0, stream>>>(tb, w2b, out_enc, b2, x2f,
      8192, 1024, 1024, 1024, 1024, 1024);
}

// Round 15
// 498.930 us; speedup vs baseline: 1.1994x; 1.1994x over previous
//
#include <hip/hip_runtime.h>

#define DEVINL __device__ __forceinline__

typedef __bf16 bf16x8 __attribute__((ext_vector_type(8)));
typedef float  f32x4  __attribute__((ext_vector_type(4)));

DEVINL unsigned short f2bf(float f) {
  return __builtin_bit_cast(unsigned short, static_cast<__bf16>(f));
}
DEVINL float bf2f(unsigned short b) {
  union { unsigned int u; float f; } v; v.u = ((unsigned int)b) << 16;
  return v.f;
}

#define GLD_LDS16(SRC, DST) \
  __builtin_amdgcn_global_load_lds((const __attribute__((address_space(1))) void*)(SRC), \
                                   (__attribute__((address_space(3))) void*)(DST), 16, 0, 0)

// ---------------------------------------------------------------------------
// Plain bf16 GEMM: C[M,N] = A[M,K] * B[N,K]^T
// EPI: 3=f32 store + res, 4=bf16 relu(x+bias), 5=f32 x+bias+res.
// SWZ: XCD A-panel grouping.
// ---------------------------------------------------------------------------
template<int EPI, bool SWZ>
__global__ __launch_bounds__(256) void gemm_bt(
    const unsigned short* __restrict__ Ap, const unsigned short* __restrict__ Bp, void* __restrict__ Cp,
    const float* __restrict__ bias, const float* __restrict__ res,
    int M, int N, int K, int lda, int ldb, int ldc)
{
  __shared__ __align__(16) char smem[16384];
  unsigned short* sB = (unsigned short*)(smem + 8192);

  const int tid = threadIdx.x;
  const int w = tid >> 6, l = tid & 63;
  const int wr = w >> 1, wc = w & 1;
  const int ntn = N >> 7;
  int tm, tn;
  if constexpr (SWZ) {
    const int x = (int)blockIdx.x & 7;
    const int g = (int)blockIdx.x >> 3;
    const int per = (M >> 7) >> 3;
    tm = x * per + g / ntn;
    tn = g - (g / ntn) * ntn;
  } else {
    tm = (int)blockIdx.x / ntn;
    tn = (int)blockIdx.x - tm * ntn;
  }

  f32x4 zero = {0.f, 0.f, 0.f, 0.f};
  f32x4 acc[4][4];
  #pragma unroll
  for (int m = 0; m < 4; ++m)
    #pragma unroll
    for (int n = 0; n < 4; ++n) acc[m][n] = zero;

  for (int k0 = 0; k0 < K; k0 += 32) {
    __syncthreads();
    const int rl = l >> 2, cl = (l & 3) << 3;
    #pragma unroll
    for (int i = 0; i < 2; ++i) {
      const unsigned short* srcA = Ap + (long)(tm*128 + w*32 + i*16 + rl) * lda + (k0 + cl);
      GLD_LDS16(srcA, (unsigned short*)smem + (w*32 + i*16) * 32);
      const unsigned short* srcB = Bp + (long)(tn*128 + w*32 + i*16 + rl) * ldb + (k0 + cl);
      GLD_LDS16(srcB, sB + (w*32 + i*16) * 32);
    }
    __syncthreads();

    bf16x8 af[4], bfr[4];
    const unsigned short* sA = (const unsigned short*)smem;
    #pragma unroll
    for (int m = 0; m < 4; ++m) {
      int row = wr*64 + m*16 + (l & 15);
      af[m] = *(const bf16x8*)(sA + row*32 + ((l >> 4) << 3));
    }
    #pragma unroll
    for (int n = 0; n < 4; ++n) {
      int row = wc*64 + n*16 + (l & 15);
      bfr[n] = *(const bf16x8*)(sB + row*32 + ((l >> 4) << 3));
    }
    #pragma unroll
    for (int m = 0; m < 4; ++m)
      #pragma unroll
      for (int n = 0; n < 4; ++n)
        acc[m][n] = __builtin_amdgcn_mfma_f32_16x16x32_bf16(af[m], bfr[n], acc[m][n], 0, 0, 0);
  }

  #pragma unroll
  for (int m = 0; m < 4; ++m) {
    #pragma unroll
    for (int n = 0; n < 4; ++n) {
      #pragma unroll
      for (int r = 0; r < 4; ++r) {
        int row = tm*128 + wr*64 + m*16 + ((l >> 4) << 2) + r;
        int col = tn*128 + wc*64 + n*16 + (l & 15);
        float v = acc[m][n][r];
        long ci = (long)row * ldc + col;
        if constexpr (EPI == 3) {
          ((float*)Cp)[ci] = v + res[ci];
        } else if constexpr (EPI == 4) {
          ((unsigned short*)Cp)[ci] = f2bf(fmaxf(v + bias[col], 0.f));
        } else if constexpr (EPI == 5) {
          ((float*)Cp)[ci] = v + bias[col] + res[ci];
        }
      }
    }
  }
}

// ---------------------------------------------------------------------------
// Fused QKV projection launch (1536 blocks):
//   [0,512)    q split-GEMM   [512,1024) k split-GEMM   [1024,1536) v GEMM^T
// ---------------------------------------------------------------------------
__global__ __launch_bounds__(256) void qkv_fused(
    const unsigned short* __restrict__ h1, const unsigned short* __restrict__ h2,
    const unsigned short* __restrict__ wq1, const unsigned short* __restrict__ wq2,
    const unsigned short* __restrict__ wk1, const unsigned short* __restrict__ wk2,
    const unsigned short* __restrict__ wv1,
    unsigned short* __restrict__ q1o, unsigned short* __restrict__ q2o,
    unsigned short* __restrict__ k1o, unsigned short* __restrict__ k2o,
    unsigned short* __restrict__ vto)
{
  __shared__ __align__(16) char smem[34816];
  const int f = (int)blockIdx.x;
  const int tid = threadIdx.x;
  const int w = tid >> 6, l = tid & 63;
  const int wr = w >> 1, wc = w & 1;

  if (f < 1024) {
    const bool isq = f < 512;
    const unsigned short* B1 = isq ? wq1 : wk1;
    const unsigned short* B2 = isq ? wq2 : wk2;
    unsigned short* C1 = isq ? q1o : k1o;
    unsigned short* C2 = isq ? q2o : k2o;
    const int sub = f & 511;
    const int x = sub & 7, g = sub >> 3;
    const int tm = x * 8 + (g >> 3);
    const int tn = g & 7;

    unsigned short* sA1 = (unsigned short*)smem;
    unsigned short* sA2 = sA1 + 4096;
    unsigned short* sB1 = sA1 + 8192;
    unsigned short* sB2 = sA1 + 12288;

    f32x4 acc[4][4];
    #pragma unroll
    for (int m = 0; m < 4; ++m)
      #pragma unroll
      for (int n = 0; n < 4; ++n) acc[m][n] = (f32x4){0.f, 0.f, 0.f, 0.f};

    const int rl = l >> 2, cl = (l & 3) << 3;

    for (int k0 = 0; k0 < 1024; k0 += 32) {
      __syncthreads();
      #pragma unroll
      for (int i = 0; i < 2; ++i) {
        const int row = w*32 + i*16;
        const long asrc = (long)(tm*128 + row + rl) * 1024 + (k0 + cl);
        const long bsrc = (long)(tn*128 + row + rl) * 1024 + (k0 + cl);
        GLD_LDS16(h1 + asrc, sA1 + row*32);
        GLD_LDS16(h2 + asrc, sA2 + row*32);
        GLD_LDS16(B1 + bsrc, sB1 + row*32);
        GLD_LDS16(B2 + bsrc, sB2 + row*32);
      }
      __syncthreads();

      bf16x8 a1[4], a2[4], bb4[4];
      int boff[4];
      #pragma unroll
      for (int m = 0; m < 4; ++m) {
        int row = wr*64 + m*16 + (l & 15);
        int aoff = row*32 + ((l >> 4) << 3);
        a1[m] = *(const bf16x8*)(sA1 + aoff);
        a2[m] = *(const bf16x8*)(sA2 + aoff);
      }
      #pragma unroll
      for (int n = 0; n < 4; ++n) {
        int row = wc*64 + n*16 + (l & 15);
        boff[n] = row*32 + ((l >> 4) << 3);
        bb4[n] = *(const bf16x8*)(sB1 + boff[n]);
      }
      #pragma unroll
      for (int m = 0; m < 4; ++m)
        #pragma unroll
        for (int n = 0; n < 4; ++n) {
          acc[m][n] = __builtin_amdgcn_mfma_f32_16x16x32_bf16(a1[m], bb4[n], acc[m][n], 0, 0, 0);
          acc[m][n] = __builtin_amdgcn_mfma_f32_16x16x32_bf16(a2[m], bb4[n], acc[m][n], 0, 0, 0);
        }
      #pragma unroll
      for (int n = 0; n < 4; ++n)
        bb4[n] = *(const bf16x8*)(sB2 + boff[n]);
      #pragma unroll
      for (int m = 0; m < 4; ++m)
        #pragma unroll
        for (int n = 0; n < 4; ++n)
          acc[m][n] = __builtin_amdgcn_mfma_f32_16x16x32_bf16(a1[m], bb4[n], acc[m][n], 0, 0, 0);
    }

    #pragma unroll
    for (int m = 0; m < 4; ++m)
      #pragma unroll
      for (int n = 0; n < 4; ++n)
        #pragma unroll
        for (int r = 0; r < 4; ++r) {
          int row = tm*128 + wr*64 + m*16 + ((l >> 4) << 2) + r;
          int col = tn*128 + wc*64 + n*16 + (l & 15);
          float v = acc[m][n][r];
          long ci = (long)row * 1024 + col;
          unsigned short hv = f2bf(v);
          C1[ci] = hv;
          C2[ci] = f2bf(v - bf2f(hv));
        }
  } else {
    const int vp = f - 1024;
    const int bbv = vp >> 6;
    const int rem = vp & 63;
    const int tm = rem >> 3, tn = rem & 7;
    const long offA = (long)bbv * 1048576;
    const long offC = (long)bbv * 1048576;
    unsigned short* sB = (unsigned short*)(smem + 8192);

    f32x4 acc[4][4];
    #pragma unroll
    for (int m = 0; m < 4; ++m)
      #pragma unroll
      for (int n = 0; n < 4; ++n) acc[m][n] = (f32x4){0.f, 0.f, 0.f, 0.f};

    for (int k0 = 0; k0 < 1024; k0 += 32) {
      __syncthreads();
      const int rl = l >> 2, cl = (l & 3) << 3;
      #pragma unroll
      for (int i = 0; i < 2; ++i) {
        const unsigned short* srcA = h1 + offA + (long)(tm*128 + w*32 + i*16 + rl) * 1024 + (k0 + cl);
        GLD_LDS16(srcA, (unsigned short*)smem + (w*32 + i*16) * 32);
        const unsigned short* srcB = wv1 + (long)(tn*128 + w*32 + i*16 + rl) * 1024 + (k0 + cl);
        GLD_LDS16(srcB, sB + (w*32 + i*16) * 32);
      }
      __syncthreads();

      bf16x8 af[4], bfr[4];
      const unsigned short* sA = (const unsigned short*)smem;
      #pragma unroll
      for (int m = 0; m < 4; ++m) {
        int row = wr*64 + m*16 + (l & 15);
        af[m] = *(const bf16x8*)(sA + row*32 + ((l >> 4) << 3));
      }
      #pragma unroll
      for (int n = 0; n < 4; ++n) {
        int row = wc*64 + n*16 + (l & 15);
        bfr[n] = *(const bf16x8*)(sB + row*32 + ((l >> 4) << 3));
      }
      #pragma unroll
      for (int m = 0; m < 4; ++m)
        #pragma unroll
        for (int n = 0; n < 4; ++n)
          acc[m][n] = __builtin_amdgcn_mfma_f32_16x16x32_bf16(af[m], bfr[n], acc[m][n], 0, 0, 0);
    }

    __syncthreads();
    unsigned short* sT = (unsigned short*)smem;
    #pragma unroll
    for (int m = 0; m < 4; ++m)
      #pragma unroll
      for (int n = 0; n < 4; ++n)
        #pragma unroll
        for (int r = 0; r < 4; ++r) {
          int rowl = wr*64 + m*16 + ((l >> 4) << 2) + r;
          int coll = wc*64 + n*16 + (l & 15);
          sT[coll*136 + rowl] = f2bf(acc[m][n][r]);
        }
    __syncthreads();
    #pragma unroll
    for (int i = 0; i < 8; ++i) {
      int idx = tid + i*256;
      int c = idx >> 4, ch = idx & 15;
      bf16x8 vv = *(const bf16x8*)(sT + c*136 + ch*8);
      *(bf16x8*)(vto + offC + (long)(tn*128 + c)*1024 + (tm*128 + ch*8)) = vv;
    }
  }
}

// ---------------------------------------------------------------------------
// Fused attention v9: 64 q-rows/block (grid 1024), 512 thr / 8 waves.
// ---------------------------------------------------------------------------
__global__ __launch_bounds__(512, 2) void attn_fused(
    const unsigned short* __restrict__ q1, const unsigned short* __restrict__ q2,
    const unsigned short* __restrict__ kn1, const unsigned short* __restrict__ kn2,
    const unsigned short* __restrict__ vt, const unsigned int* __restrict__ mbits,
    float* __restrict__ attn, unsigned short* __restrict__ outm)
{
  __shared__ __align__(16) char smem[131072];  // q(32K)/red(2K) then P(128K)
  char* q1l = smem;
  char* q2l = smem + 16384;
  float* red = (float*)(smem + 32768);

  const int tid = threadIdx.x;
  const int w = tid >> 6, l = tid & 63;
  const int l15 = l & 15, l4 = l >> 4;

  const int f = (int)blockIdx.x;
  const int xcd = f & 7;
  const int j = f >> 3;
  const int z = xcd * 8 + (j >> 4);
  const int row0 = (j & 15) * 64;

  const int bb = z >> 3, hh = z & 7;
  const long base = (long)bb * 1048576;
  const int ocol = hh * 128;
  const int key0 = w * 128;

  #pragma unroll
  for (int rep = 0; rep < 2; ++rep) {
    int idx = rep*512 + tid;
    int row = idx >> 4;
    int g   = idx & 15;
    long gsrc = base + (long)(row0 + row) * 1024 + (ocol + g*8);
    int byte = (row*256 + g*16) ^ ((row & 7) << 4);
    *(bf16x8*)(q1l + byte) = *(const bf16x8*)(q1 + gsrc);
    *(bf16x8*)(q2l + byte) = *(const bf16x8*)(q2 + gsrc);
  }
  __syncthreads();

  f32x4 s[4][8];
  #pragma unroll
  for (int mf = 0; mf < 4; ++mf)
    #pragma unroll
    for (int nf = 0; nf < 8; ++nf) s[mf][nf] = (f32x4){0.f, 0.f, 0.f, 0.f};

  #pragma unroll
  for (int ks = 0; ks < 4; ++ks) {
    bf16x8 a1[4], a2[4];
    #pragma unroll
    for (int mf = 0; mf < 4; ++mf) {
      int row = mf*16 + l15;
      int byte = (row*256 + (ks*32 + l4*8)*2) ^ ((row & 7) << 4);
      a1[mf] = *(const bf16x8*)(q1l + byte);
      a2[mf] = *(const bf16x8*)(q2l + byte);
    }
    #pragma unroll
    for (int np = 0; np < 4; ++np) {
      bf16x8 b1[2], b2[2];
      #pragma unroll
      for (int t = 0; t < 2; ++t) {
        int nf = np*2 + t;
        long bi = base + (long)(key0 + nf*16 + l15) * 1024 + (ocol + ks*32 + l4*8);
        b1[t] = *(const bf16x8*)(kn1 + bi);
        b2[t] = *(const bf16x8*)(kn2 + bi);
      }
      #pragma unroll
      for (int t = 0; t < 2; ++t) {
        int nf = np*2 + t;
        #pragma unroll
        for (int mf = 0; mf < 4; ++mf) {
          s[mf][nf] = __builtin_amdgcn_mfma_f32_16x16x32_bf16(a1[mf], b1[t], s[mf][nf], 0, 0, 0);
          s[mf][nf] = __builtin_amdgcn_mfma_f32_16x16x32_bf16(a2[mf], b1[t], s[mf][nf], 0, 0, 0);
          s[mf][nf] = __builtin_amdgcn_mfma_f32_16x16x32_bf16(a1[mf], b2[t], s[mf][nf], 0, 0, 0);
        }
      }
    }
  }

  #pragma unroll
  for (int mf = 0; mf < 4; ++mf) {
    #pragma unroll
    for (int r = 0; r < 4; ++r) {
      int mg = row0 + mf*16 + l4*4 + r;
      const unsigned int* wrow = mbits + (long)bb*32768 + (long)mg*32 + w*4;
      unsigned int wd[4];
      #pragma unroll
      for (int jj = 0; jj < 4; ++jj) wd[jj] = wrow[jj];
      #pragma unroll
      for (int nf = 0; nf < 8; ++nf) {
        unsigned int bit = (wd[nf >> 1] >> (((nf & 1) << 4) + l15)) & 1u;
        if (!bit) s[mf][nf][r] = -1e9f;
      }
    }
  }

  float mx[4][4];
  #pragma unroll
  for (int mf = 0; mf < 4; ++mf)
    #pragma unroll
    for (int r = 0; r < 4; ++r) {
      float m = s[mf][0][r];
      #pragma unroll
      for (int nf = 1; nf < 8; ++nf) m = fmaxf(m, s[mf][nf][r]);
      #pragma unroll
      for (int o = 1; o < 16; o <<= 1) m = fmaxf(m, __shfl_xor(m, o, 64));
      if (l15 == 0) red[w*64 + mf*16 + l4*4 + r] = m;
    }
  __syncthreads();
  #pragma unroll
  for (int mf = 0; mf < 4; ++mf)
    #pragma unroll
    for (int r = 0; r < 4; ++r) {
      int ml = mf*16 + l4*4 + r;
      float m = red[ml];
      #pragma unroll
      for (int ww = 1; ww < 8; ++ww) m = fmaxf(m, red[ww*64 + ml]);
      mx[mf][r] = m;
    }
  __syncthreads();

  float sm[4][4];
  #pragma unroll
  for (int mf = 0; mf < 4; ++mf)
    #pragma unroll
    for (int r = 0; r < 4; ++r) sm[mf][r] = 0.f;
  #pragma unroll
  for (int mf = 0; mf < 4; ++mf)
    #pragma unroll
    for (int nf = 0; nf < 8; ++nf)
      #pragma unroll
      for (int r = 0; r < 4; ++r) {
        float e = __expf(s[mf][nf][r] - mx[mf][r]);
        s[mf][nf][r] = e;
        sm[mf][r] += e;
      }
  #pragma unroll
  for (int mf = 0; mf < 4; ++mf)
    #pragma unroll
    for (int r = 0; r < 4; ++r) {
      float t = sm[mf][r];
      #pragma unroll
      for (int o = 1; o < 16; o <<= 1) t += __shfl_xor(t, o, 64);
      if (l15 == 0) red[w*64 + mf*16 + l4*4 + r] = t;
    }
  __syncthreads();
  float inv[4][4];
  #pragma unroll
  for (int mf = 0; mf < 4; ++mf)
    #pragma unroll
    for (int r = 0; r < 4; ++r) {
      int ml = mf*16 + l4*4 + r;
      float t = red[ml];
      #pragma unroll
      for (int ww = 1; ww < 8; ++ww) t += red[ww*64 + ml];
      inv[mf][r] = 1.f / t;
    }
  __syncthreads();

  float* arow = attn + (long)(bb*8 + hh) * 1048576;
  #pragma unroll
  for (int mf = 0; mf < 4; ++mf)
    #pragma unroll
    for (int nf = 0; nf < 8; ++nf)
      #pragma unroll
      for (int r = 0; r < 4; ++r) {
        int ml = mf*16 + l4*4 + r;
        int kcol = key0 + nf*16 + l15;
        float a = s[mf][nf][r] * inv[mf][r];
        int byte = (ml*2048 + kcol*2) ^ ((ml & 7) << 4);
        *(unsigned short*)(smem + byte) = f2bf(a);
        arow[(long)(row0 + ml) * 1024 + kcol] = a;
      }
  asm volatile("s_waitcnt lgkmcnt(0)" ::: "memory");
  __builtin_amdgcn_sched_barrier(0);
  __builtin_amdgcn_s_barrier();
  __builtin_amdgcn_sched_barrier(0);

  f32x4 o[4];
  #pragma unroll
  for (int mf = 0; mf < 4; ++mf) o[mf] = (f32x4){0.f, 0.f, 0.f, 0.f};
  #pragma unroll
  for (int kq = 0; kq < 8; ++kq) {
    bf16x8 vb[4];
    #pragma unroll
    for (int t = 0; t < 4; ++t) {
      int kb = (kq*4 + t)*32 + l4*8;
      vb[t] = *(const bf16x8*)(vt + base + (long)(ocol + w*16 + l15) * 1024 + kb);
    }
    #pragma unroll
    for (int t = 0; t < 4; ++t) {
      int kb = (kq*4 + t)*32 + l4*8;
      bf16x8 pa[4];
      #pragma unroll
      for (int mf = 0; mf < 4; ++mf) {
        int ml = mf*16 + l15;
        int byte = (ml*2048 + kb*2) ^ ((ml & 7) << 4);
        pa[mf] = *(const bf16x8*)(smem + byte);
      }
      #pragma unroll
      for (int mf = 0; mf < 4; ++mf)
        o[mf] = __builtin_amdgcn_mfma_f32_16x16x32_bf16(pa[mf], vb[t], o[mf], 0, 0, 0);
    }
  }

  #pragma unroll
  for (int mf = 0; mf < 4; ++mf)
    #pragma unroll
    for (int r = 0; r < 4; ++r) {
      int row = row0 + mf*16 + l4*4 + r;
      int col = ocol + w*16 + l15;
      outm[(long)(bb*1024 + row) * 1024 + col] = f2bf(o[mf][r]);
    }
}

// ---------------------------------------------------------------------------
// prep: all weight casts/splits + mask bit-pack in ONE launch (8192 blocks).
// ---------------------------------------------------------------------------
__global__ __launch_bounds__(256) void prep(
    const float* __restrict__ wq, const float* __restrict__ wk,
    const float* __restrict__ wv, const float* __restrict__ wo,
    const float* __restrict__ w1, const float* __restrict__ w2,
    const int* __restrict__ mask,
    unsigned short* __restrict__ wq1, unsigned short* __restrict__ wq2,
    unsigned short* __restrict__ wk1, unsigned short* __restrict__ wk2,
    unsigned short* __restrict__ wv1, unsigned short* __restrict__ wob,
    unsigned short* __restrict__ w1b, unsigned short* __restrict__ w2b,
    unsigned int* __restrict__ bits)
{
  const int f = (int)blockIdx.x;
  const int tid = threadIdx.x;
  if (f < 2048) {
    const float* src = (f < 1024) ? wq : wk;
    unsigned short* hi = (f < 1024) ? wq1 : wk1;
    unsigned short* lo = (f < 1024) ? wq2 : wk2;
    long i = (long)(f & 1023) * 256 + tid;
    float4 v = ((const float4*)src)[i];
    ushort4 h, l4;
    h.x = f2bf(v.x); l4.x = f2bf(v.x - bf2f(h.x));
    h.y = f2bf(v.y); l4.y = f2bf(v.y - bf2f(h.y));
    h.z = f2bf(v.z); l4.z = f2bf(v.z - bf2f(h.z));
    h.w = f2bf(v.w); l4.w = f2bf(v.w - bf2f(h.w));
    ((ushort4*)hi)[i] = h;
    ((ushort4*)lo)[i] = l4;
  } else if (f < 6144) {
    const int sel = (f - 2048) >> 10;
    const float* src = (sel == 0) ? wv : (sel == 1) ? wo : (sel == 2) ? w1 : w2;
    unsigned short* dst = (sel == 0) ? wv1 : (sel == 1) ? wob : (sel == 2) ? w1b : w2b;
    long i = (long)((f - 2048) & 1023) * 256 + tid;
    float4 v = ((const float4*)src)[i];
    ushort4 h;
    h.x = f2bf(v.x); h.y = f2bf(v.y); h.z = f2bf(v.z); h.w = f2bf(v.w);
    ((ushort4*)dst)[i] = h;
  } else {
    int w = tid >> 6, l = tid & 63;
    long rowid = (long)(f - 6144) * 4 + w;
    const int* mrow = mask + rowid * 1024;
    unsigned int* brow = bits + rowid * 32;
    #pragma unroll
    for (int it = 0; it < 16; ++it) {
      unsigned long long b = __ballot(mrow[it*64 + l] != 0);
      if (l == 0) { brow[it*2] = (unsigned int)b; brow[it*2 + 1] = (unsigned int)(b >> 32); }
    }
  }
}

// ---------------------------------------------------------------------------
// LayerNorm over (d_model, seq) per batch: two-stage deterministic reduction.
// ---------------------------------------------------------------------------
__global__ __launch_bounds__(256) void ln_stats1(const float* __restrict__ x, float2* __restrict__ part) {
  __shared__ float2 sred[4];
  int b = blockIdx.y, blk = blockIdx.x;
  const float4* xp = (const float4*)(x + (long)b * 1048576 + (long)blk * 8192);
  float s = 0.f, ss = 0.f;
  for (int i = threadIdx.x; i < 2048; i += 256) {
    float4 v = xp[i];
    s  += v.x + v.y + v.z + v.w;
    ss += v.x*v.x + v.y*v.y + v.z*v.z + v.w*v.w;
  }
  #pragma unroll
  for (int o = 32; o; o >>= 1) { s += __shfl_down(s, o, 64); ss += __shfl_down(ss, o, 64); }
  if ((threadIdx.x & 63) == 0) sred[threadIdx.x >> 6] = make_float2(s, ss);
  __syncthreads();
  if (threadIdx.x == 0) {
    float S = 0.f, SS = 0.f;
    #pragma unroll
    for (int j = 0; j < 4; ++j) { S += sred[j].x; SS += sred[j].y; }
    part[b * 128 + blk] = make_float2(S, SS);
  }
}

__global__ __launch_bounds__(128) void ln_stats2(const float2* __restrict__ part, float2* __restrict__ stats,
                                                 float invN, float eps) {
  __shared__ float2 tmp[2];
  int b = blockIdx.x;
  float2 p = part[b * 128 + threadIdx.x];
  float s = p.x, ss = p.y;
  #pragma unroll
  for (int o = 32; o; o >>= 1) { s += __shfl_down(s, o, 64); ss += __shfl_down(ss, o, 64); }
  if ((threadIdx.x & 63) == 0) tmp[threadIdx.x >> 6] = make_float2(s, ss);
  __syncthreads();
  if (threadIdx.x == 0) {
    float S = tmp[0].x + tmp[1].x, SS = tmp[0].y + tmp[1].y;
    float mu = S * invN;
    float var = SS * invN - mu * mu;
    stats[b] = make_float2(mu, rsqrtf(var + eps));
  }
}

template<bool LO>
__global__ __launch_bounds__(256) void ln_apply(const float* __restrict__ x, const float* __restrict__ g,
                                                const float* __restrict__ be, const float2* __restrict__ stats,
                                                unsigned short* __restrict__ hi, unsigned short* __restrict__ lo) {
  long i = (long)blockIdx.x * 256 + threadIdx.x;
  long e = i << 2;
  int b   = (int)(e >> 20);
  int rem = (int)(e & 1048575);
  float2 st = stats[b];
  float4 xv = ((const float4*)x)[i];
  float4 gv = *(const float4*)(g + rem);
  float4 bv = *(const float4*)(be + rem);
  float h0 = (xv.x - st.x) * st.y * gv.x + bv.x;
  float h1 = (xv.y - st.x) * st.y * gv.y + bv.y;
  float h2 = (xv.z - st.x) * st.y * gv.z + bv.z;
  float h3 = (xv.w - st.x) * st.y * gv.w + bv.w;
  ushort4 h;
  h.x = f2bf(h0); h.y = f2bf(h1); h.z = f2bf(h2); h.w = f2bf(h3);
  ((ushort4*)hi)[i] = h;
  if (LO) {
    ushort4 l4;
    l4.x = f2bf(h0 - bf2f(h.x)); l4.y = f2bf(h1 - bf2f(h.y));
    l4.z = f2bf(h2 - bf2f(h.z)); l4.w = f2bf(h3 - bf2f(h.w));
    ((ushort4*)lo)[i] = l4;
  }
}

// k-head-norm from split bf16 k, vectorized: 4 d-columns per thread.
__global__ __launch_bounds__(256) void knorm_split2(const unsigned short* __restrict__ k1,
                                                    const unsigned short* __restrict__ k2,
                                                    unsigned short* __restrict__ kn1,
                                                    unsigned short* __restrict__ kn2) {
  int t = blockIdx.x * 256 + threadIdx.x;   // 256K threads: (b, m, d4)
  int b = t >> 15;
  int rem = t & 32767;
  int m = rem >> 5;
  int d4 = rem & 31;
  long base = (long)b * 1048576 + (long)m * 1024 + d4 * 4;
  float v[8][4];
  float s[4] = {0.f, 0.f, 0.f, 0.f};
  #pragma unroll
  for (int h = 0; h < 8; ++h) {
    ushort4 a = *(const ushort4*)(k1 + base + h * 128);
    ushort4 c = *(const ushort4*)(k2 + base + h * 128);
    v[h][0] = bf2f(a.x) + bf2f(c.x);
    v[h][1] = bf2f(a.y) + bf2f(c.y);
    v[h][2] = bf2f(a.z) + bf2f(c.z);
    v[h][3] = bf2f(a.w) + bf2f(c.w);
    #pragma unroll
    for (int d = 0; d < 4; ++d) s[d] += v[h][d] * v[h][d];
  }
  float rn[4];
  #pragma unroll
  for (int d = 0; d < 4; ++d) rn[d] = 1.f / fmaxf(sqrtf(s[d]), 1e-12f);
  #pragma unroll
  for (int h = 0; h < 8; ++h) {
    ushort4 hv, lv;
    float f0 = v[h][0] * rn[0], f1 = v[h][1] * rn[1];
    float f2 = v[h][2] * rn[2], f3 = v[h][3] * rn[3];
    hv.x = f2bf(f0); lv.x = f2bf(f0 - bf2f(hv.x));
    hv.y = f2bf(f1); lv.y = f2bf(f1 - bf2f(hv.y));
    hv.z = f2bf(f2); lv.z = f2bf(f2 - bf2f(hv.z));
    hv.w = f2bf(f3); lv.w = f2bf(f3 - bf2f(hv.w));
    *(ushort4*)(kn1 + base + h * 128) = hv;
    *(ushort4*)(kn2 + base + h * 128) = lv;
  }
}

// ---------------------------------------------------------------------------
extern "C" void kernel_launch(void* const* d_in, const int* in_sizes, int n_in,
                              void* d_out, int out_size, void* d_ws, size_t ws_size,
                              hipStream_t stream) {
  const float* enc  = (const float*)d_in[0];
  const int*   mask = (const int*)d_in[1];
  const float* ln1g = (const float*)d_in[2];
  const float* ln1b = (const float*)d_in[3];
  const float* wq   = (const float*)d_in[4];
  const float* wk   = (const float*)d_in[5];
  const float* wv   = (const float*)d_in[6];
  const float* wo   = (const float*)d_in[7];
  const float* ln2g = (const float*)d_in[8];
  const float* ln2b = (const float*)d_in[9];
  const float* w1   = (const float*)d_in[10];
  const float* b1   = (const float*)d_in[11];
  const float* w2   = (const float*)d_in[12];
  const float* b2   = (const float*)d_in[13];

  float* out_enc  = (float*)d_out;
  float* out_attn = out_enc + 8388608;   // [8, 8, 1024, 1024]

  const size_t MB = 1ull << 20;
  char* ws = (char*)d_ws;
  unsigned short* h1   = (unsigned short*)(ws + 0 * MB);     // LN1 hi  [8192,1024]
  unsigned short* h2   = (unsigned short*)(ws + 16 * MB);    // LN1 lo
  unsigned short* q1   = (unsigned short*)(ws + 32 * MB);    // q hi (later h2b)
  unsigned short* q2   = (unsigned short*)(ws + 48 * MB);    // q lo (later tb)
  unsigned short* k1r  = (unsigned short*)(ws + 64 * MB);    // k hi (raw)
  unsigned short* k2r  = (unsigned short*)(ws + 80 * MB);    // k lo (raw)
  unsigned short* kn1  = (unsigned short*)(ws + 96 * MB);    // k-normed hi
  unsigned short* kn2  = (unsigned short*)(ws + 112 * MB);   // k-normed lo
  unsigned short* vt   = (unsigned short*)(ws + 128 * MB);   // v^T per batch [b][o][m]
  unsigned short* outm = (unsigned short*)(ws + 144 * MB);   // attn@v merged [b][m][o]
  float*          x2f  = (float*)(ws + 160 * MB);            // attn-out + residual, f32
  unsigned short* h2b  = (unsigned short*)(ws + 32 * MB);    // LN2 out bf16 (reuse q1)
  unsigned short* tb   = (unsigned short*)(ws + 48 * MB);    // FFN1 out bf16 (reuse q2)
  unsigned short* wq1  = (unsigned short*)(ws + 192 * MB);
  unsigned short* wq2  = (unsigned short*)(ws + 194 * MB);
  unsigned short* wk1  = (unsigned short*)(ws + 196 * MB);
  unsigned short* wk2  = (unsigned short*)(ws + 198 * MB);
  unsigned short* wv1  = (unsigned short*)(ws + 200 * MB);
  unsigned short* wob  = (unsigned short*)(ws + 202 * MB);
  unsigned short* w1b  = (unsigned short*)(ws + 204 * MB);
  unsigned short* w2b  = (unsigned short*)(ws + 206 * MB);
  float2* part  = (float2*)(ws + 208 * MB);
  float2* stats = part + 1024;
  unsigned int* mbits = (unsigned int*)(ws + 209 * MB);      // 1 MB packed mask

  const float invN = 1.f / 1048576.f;

  // ---- LN1 ----
  ln_stats1<<<dim3(128, 8), 256, 0, stream>>>(enc, part);
  ln_stats2<<<dim3(8), 128, 0, stream>>>(part, stats, invN, 1e-6f);
  ln_apply<true><<<dim3(8192), 256, 0, stream>>>(enc, ln1g, ln1b, stats, h1, h2);

  // ---- all weight casts + mask pack in one launch ----
  prep<<<dim3(8192), 256, 0, stream>>>(wq, wk, wv, wo, w1, w2, mask,
      wq1, wq2, wk1, wk2, wv1, wob, w1b, w2b, mbits);

  // ---- q/k/v projections fused in one launch ----
  qkv_fused<<<dim3(1536), 256, 0, stream>>>(h1, h2, wq1, wq2, wk1, wk2, wv1,
      q1, q2, k1r, k2r, vt);

  // ---- k head-norm + split (vectorized) ----
  knorm_split2<<<dim3(1024), 256, 0, stream>>>(k1r, k2r, kn1, kn2);

  // ---- fused attention: logits + mask + softmax + attn store + PV ----
  attn_fused<<<dim3(1024), 512, 0, stream>>>(q1, q2, kn1, kn2, vt, mbits, out_attn, outm);

  // ---- output projection + residual (XCD-grouped) ----
  gemm_bt<3, true><<<dim3(512), 256, 0, stream>>>(outm, wob, x2f, nullptr, enc,
      8192, 1024, 1024, 1024, 1024, 1024);

  // ---- LN2 ----
  ln_stats1<<<dim3(128, 8), 256, 0, stream>>>(x2f, part);
  ln_stats2<<<dim3(8), 128, 0, stream>>>(part, stats, invN, 1e-6f);
  ln_apply<false><<<dim3(8192), 256, 0, stream>>>(x2f, ln2g, ln2b, stats, h2b, nullptr);

  // ---- FFN (XCD-grouped) ----
  gemm_bt<4, true><<<dim3(512), 256, 0, stream>>>(h2b, w1b, tb, b1, nullptr,
      8192, 1024, 1024, 1024, 1024, 1024);
  gemm_bt<5, true><<<dim3(512), 256, 0, stream>>>(tb, w2b, out_enc, b2, x2f,
      8192, 1024, 1024, 1024, 1024, 1024);
}